// Round 19
// baseline (78.315 us; speedup 1.0000x reference)
//
#include <hip/hip_runtime.h>
#include <math.h>

#define BB 4096
#define DD 1024
#define KK 5
#define PP 1323

// (2*pi)^(-3/2)
#define INV_2PI_POW15 0.06349363593424097f

// ---- fused config ----
#define GR    16       // b-rows per block tile
#define NWV   8        // waves per block (512 threads)
#define HT    512      // block threads
#define RST   13       // s_red inner stride (12 + 1)
#define CSTR  49       // s_c inner stride
#define NPASS 42       // ceil(1323 / 32) p-passes of 32 rows
#define NSPL  4        // p-split factor (grid = NSPL * 256)

typedef short  bf16x8 __attribute__((ext_vector_type(8)));
typedef float  f32x4  __attribute__((ext_vector_type(4)));

__device__ __forceinline__ short f2bf(float f) {
    union { float f; unsigned u; } x; x.f = f;
    const unsigned r = x.u + 0x7fffu + ((x.u >> 16) & 1u);  // RNE
    return (short)(r >> 16);
}
__device__ __forceinline__ float softplus_f(float x) {
    return (x > 20.f) ? x : log1pf(expf(x));
}

// ---------------------------------------------------------------------------
// Single fused kernel, p-split for occupancy. Grid 1024 = (4 p-quarters s) x
// (256 b-tiles bt). Every block computes the head for its 16 b-rows
// (redundant x4 across s -- W/rep reads are L3-resident so the redundancy is
// cache-absorbed), then evaluates p-passes {s, s+4, ...} of its 16 columns.
// No cross-block dependency, no barrier, no intermediate global buffer.
// Lout written only by s==0 blocks.
// ---------------------------------------------------------------------------
__global__ __launch_bounds__(HT, 2) void fused_kernel(
    const float* __restrict__ rep,
    const float* __restrict__ dxyz,
    const float* __restrict__ Wmix,
    const float* __restrict__ bmix,
    const float* __restrict__ Wmean,
    const float* __restrict__ bmean,
    const float* __restrict__ Wscale,
    const float* __restrict__ bscale,
    float* __restrict__ out,
    float* __restrict__ Lout)
{
    __shared__ float s_red[NWV][64][RST];   // 26.6 KB
    __shared__ float s_c[GR][CSTR];         // 3.1 KB
    __shared__ float s_L[GR][KK][6];        // 1.9 KB
    __shared__ float s_par[GR][50];         // 3.2 KB

    const int t  = threadIdx.x;
    const int w  = t >> 6;          // wave 0..7
    const int l  = t & 63;
    const int lm = l & 15;
    const int lk = (l >> 4) * 8;
    const int s  = blockIdx.x >> 8;         // p-quarter 0..3
    const int bt = blockIdx.x & 255;        // b-tile
    const int b0 = bt * GR;

    // ======================= Phase A: head =================================
    // B-fragments direct from raw W (predicated strided gather, L2/L3-hit)
    bf16x8 bh[4][3];
#pragma unroll
    for (int nt = 0; nt < 3; ++nt) {
        const int j0 = nt * 16 + lm;
        const float* bp; int ncol, col;
        if (j0 < 5)       { bp = Wmix;   ncol = 5;  col = j0; }
        else if (j0 < 17) { bp = Wmean;  ncol = 12; col = j0 - 5; }
        else if (j0 < 47) { bp = Wscale; ncol = 30; col = j0 - 17; }
        else              { bp = Wmix;   ncol = 0;  col = 0; }   // j0==47 pad
        const bool valid = (j0 < 47);
#pragma unroll
        for (int kt = 0; kt < 4; ++kt) {
            const int k0 = (w * 4 + kt) * 32 + lk;
            float f[8];
#pragma unroll
            for (int e = 0; e < 8; ++e)
                f[e] = valid ? bp[(size_t)(k0 + e) * ncol + col] : 0.f;
#pragma unroll
            for (int e = 0; e < 8; ++e)
                bh[kt][nt][e] = f2bf(f[e]);
        }
    }

    // A (rep) loads upfront
    f32x4 a0[4], a1[4];
#pragma unroll
    for (int kt = 0; kt < 4; ++kt) {
        const int kof = (w * 4 + kt) * 32 + lk;
        const float* arow = rep + (size_t)(b0 + lm) * DD + kof;
        a0[kt] = *(const f32x4*)(arow);
        a1[kt] = *(const f32x4*)(arow + 4);
    }

    // convert + MFMA
    f32x4 acc[3] = {f32x4{0,0,0,0}, f32x4{0,0,0,0}, f32x4{0,0,0,0}};
#pragma unroll
    for (int kt = 0; kt < 4; ++kt) {
        bf16x8 ah;
#pragma unroll
        for (int u = 0; u < 4; ++u) {
            ah[u]     = f2bf(a0[kt][u]);
            ah[u + 4] = f2bf(a1[kt][u]);
        }
#pragma unroll
        for (int nt = 0; nt < 3; ++nt)
            acc[nt] = __builtin_amdgcn_mfma_f32_16x16x32_bf16(ah, bh[kt][nt], acc[nt], 0, 0, 0);
    }

    // 8-deep cross-wave reduce via LDS
#pragma unroll
    for (int nt = 0; nt < 3; ++nt)
#pragma unroll
        for (int r = 0; r < 4; ++r)
            s_red[w][l][nt * 4 + r] = acc[nt][r];
    __syncthreads();

    // cooperative sum into s_c[b_loc][j]; C layout [m89]:
    // col(=j) = lane&15, row(=b_loc) = (lane>>4)*4 + reg
    for (int e = t; e < GR * 47; e += HT) {
        const int b_loc = e & 15;
        const int j     = e >> 4;
        const int lane  = ((b_loc >> 2) << 4) | (j & 15);
        const int reg   = ((j >> 4) << 2) | (b_loc & 3);
        float sv = 0.f;
#pragma unroll
        for (int q = 0; q < NWV; ++q) sv += s_red[q][lane][reg];
        s_c[b_loc][j] = sv;
    }
    __syncthreads();

    // tail: 80 threads = 16 b x 5 k -> s_L + s_par
    if (t < GR * KK) {
        const int k     = t >> 4;
        const int b_loc = t & 15;

        float logits[KK];
#pragma unroll
        for (int kk = 0; kk < KK; ++kk) logits[kk] = s_c[b_loc][kk] + bmix[kk];

        float m[3];
#pragma unroll
        for (int c = 0; c < 3; ++c)
            m[c] = (k > 0) ? (s_c[b_loc][5 + (k - 1) * 3 + c] + bmean[(k - 1) * 3 + c]) : 0.f;

        float sc[6];
#pragma unroll
        for (int c = 0; c < 6; ++c)
            sc[c] = s_c[b_loc][17 + k * 6 + c] + bscale[k * 6 + c];

        float mx = logits[0];
#pragma unroll
        for (int kk = 1; kk < KK; ++kk) mx = fmaxf(mx, logits[kk]);
        float den = 0.f;
#pragma unroll
        for (int kk = 0; kk < KK; ++kk) den += expf(logits[kk] - mx);
        const float wgt = expf(logits[k] - mx) / den;

        const float L00 = softplus_f(sc[0]);
        const float L10 = sc[1];
        const float L11 = softplus_f(sc[2]);
        const float L20 = sc[3];
        const float L21 = sc[4];
        const float L22 = softplus_f(sc[5]);

        const float r00 = 1.f / L00;
        const float r11 = 1.f / L11;
        const float r22 = 1.f / L22;
        const float a   = wgt * r00 * r11 * r22 * INV_2PI_POW15;

        s_L[b_loc][k][0] = L00;
        s_L[b_loc][k][1] = L10;
        s_L[b_loc][k][2] = L11;
        s_L[b_loc][k][3] = L20;
        s_L[b_loc][k][4] = L21;
        s_L[b_loc][k][5] = L22;

        float pv[10] = { m[0], m[1], m[2], r00, L10, r11, L20, L21, r22, a };
#pragma unroll
        for (int i = 0; i < 10; ++i)
            s_par[b_loc][k * 10 + i] = pv[i];
    }
    __syncthreads();

    // coalesced Lout write (s==0 copies only): 720 contiguous floats
    if (s == 0) {
        for (int e = t; e < GR * KK * 9; e += HT) {
            const int b_loc = e / 45;
            const int rem   = e - b_loc * 45;
            const int k     = rem / 9;
            const int e9    = rem - k * 9;
            const int rr    = e9 / 3;
            const int cc    = e9 - rr * 3;
            const float v = (cc > rr) ? 0.f : s_L[b_loc][k][(rr * (rr + 1)) / 2 + cc];
            Lout[(size_t)b0 * 45 + e] = v;
        }
    }

    // ======================= Phase B: eval (p-quarter s) ===================
    const int b_loc = t & 15;
    const int prow  = t >> 4;       // 0..31
    const int bg    = b0 + b_loc;

    float pr[50];
#pragma unroll
    for (int i = 0; i < 50; ++i) pr[i] = s_par[b_loc][i];

    const int nj = (NPASS - s + NSPL - 1) / NSPL;   // 10 or 11 passes

    int p = s * 32 + prow;
    float x0 = 0.f, x1 = 0.f, x2 = 0.f;
    if (p < PP) {
        const float* xv = dxyz + ((size_t)p * BB + bg) * 3;
        x0 = xv[0]; x1 = xv[1]; x2 = xv[2];
    }

#pragma unroll 1
    for (int j = 0; j < nj; ++j) {
        const int pn = p + NSPL * 32;
        float y0 = 0.f, y1 = 0.f, y2 = 0.f;
        if (j + 1 < nj && pn < PP) {
            const float* yv = dxyz + ((size_t)pn * BB + bg) * 3;
            y0 = yv[0]; y1 = yv[1]; y2 = yv[2];
        }

        if (p < PP) {
            float res = 0.f;
#pragma unroll
            for (int k = 0; k < KK; ++k) {
                const float d0 = x0 - pr[k * 10 + 0];
                const float d1 = x1 - pr[k * 10 + 1];
                const float d2 = x2 - pr[k * 10 + 2];
                const float z0 = d0 * pr[k * 10 + 3];
                const float z1 = fmaf(-pr[k * 10 + 4], z0, d1) * pr[k * 10 + 5];
                const float z2 = fmaf(-pr[k * 10 + 7], z1, fmaf(-pr[k * 10 + 6], z0, d2)) * pr[k * 10 + 8];
                const float q  = fmaf(z2, z2, fmaf(z1, z1, z0 * z0));
                res = fmaf(pr[k * 10 + 9], __expf(-0.5f * q), res);
            }
            out[(size_t)p * BB + bg] = res;
        }

        x0 = y0; x1 = y1; x2 = y2;
        p = pn;
    }
}

extern "C" void kernel_launch(void* const* d_in, const int* in_sizes, int n_in,
                              void* d_out, int out_size, void* d_ws, size_t ws_size,
                              hipStream_t stream) {
    const float* rep    = (const float*)d_in[0];
    const float* dxyz   = (const float*)d_in[1];
    const float* Wmix   = (const float*)d_in[2];
    const float* bmix   = (const float*)d_in[3];
    const float* Wmean  = (const float*)d_in[4];
    const float* bmean  = (const float*)d_in[5];
    const float* Wscale = (const float*)d_in[6];
    const float* bscale = (const float*)d_in[7];

    float* out  = (float*)d_out;
    float* Lout = out + (size_t)BB * PP;          // second tuple output

    fused_kernel<<<NSPL * 256, HT, 0, stream>>>(rep, dxyz, Wmix, bmix, Wmean, bmean,
                                                Wscale, bscale, out, Lout);
}

// Round 20
// 34.604 us; speedup vs baseline: 2.2632x; 2.2632x over previous
//
#include <hip/hip_runtime.h>
#include <math.h>

#define BB 4096
#define DD 1024
#define KK 5
#define PP 1323
#define PTS 7          // points per ptile; 1323 = 189 * 7
#define NPT 189        // p-tiles

#define LOG2E    1.4426950408889634f
#define LN2PI15  2.7568155996140185f   // 1.5 * ln(2*pi)

// ---- head config (R16-proven) ----
#define GR   16        // rows per head block -> 256 blocks
#define NWV  8         // waves per head block (512 threads)
#define HT   512       // head block threads
#define RST  13        // s_red inner stride (12 + 1)
#define CSTR 49        // s_c inner stride
#define NG   13        // param groups of 4
#define WPKN 49152     // packed weight elements

typedef short  bf16x8 __attribute__((ext_vector_type(8)));
typedef float  f32x4  __attribute__((ext_vector_type(4)));

__device__ __forceinline__ short f2bf(float f) {
    union { float f; unsigned u; } x; x.f = f;
    const unsigned r = x.u + 0x7fffu + ((x.u >> 16) & 1u);  // RNE
    return (short)(r >> 16);
}
__device__ __forceinline__ float softplus_f(float x) {
    return (x > 20.f) ? x : log1pf(expf(x));
}

__device__ __forceinline__ int wpk_index(int k, int j) {
    // Wpk[chunk][nt][lane][8]: k = chunk*32 + (lane>>4)*8 + ee, j = nt*16 + (lane&15)
    const int chunk = k >> 5;
    const int kin   = k & 31;
    const int lane  = ((kin >> 3) << 4) | (j & 15);
    const int nt    = j >> 4;
    const int ee    = k & 7;
    return ((chunk * 3 + nt) * 64 + lane) * 8 + ee;
}

// ---------------------------------------------------------------------------
// Kernel 0 (R16-identical): pack weights -> bf16 fragment order, coalesced.
// ---------------------------------------------------------------------------
__global__ __launch_bounds__(256) void pack_kernel(
    const float* __restrict__ Wmix,
    const float* __restrict__ Wmean,
    const float* __restrict__ Wscale,
    short* __restrict__ Wpk)
{
    const int e = blockIdx.x * 256 + threadIdx.x;   // 0 .. 49151
    int k, j; float v;
    if (e < 5120) {                       // Wmix: [1024][5]
        k = e / 5;  j = e - k * 5;
        v = Wmix[e];
    } else if (e < 17408) {               // Wmean: [1024][12]
        const int i = e - 5120;
        k = i / 12; j = 5 + (i - k * 12);
        v = Wmean[i];
    } else if (e < 48128) {               // Wscale: [1024][30]
        const int i = e - 17408;
        k = i / 30; j = 17 + (i - k * 30);
        v = Wscale[i];
    } else {                              // zero-fill j = 47
        k = e - 48128; j = 47; v = 0.f;
    }
    Wpk[wpk_index(k, j)] = f2bf(v);
}

// ---------------------------------------------------------------------------
// Kernel 1: fused head (R16 structure). 256 blocks x 512 thr (8 waves).
// Tail now emits a 10-coefficient exp2-domain POLYNOMIAL per (b,k):
//   arg2(x) = c0 + q00 x0^2 + q01 x0x1 + q02 x0x2 + q11 x1^2 + q12 x1x2
//           + q22 x2^2 + l0 x0 + l1 x1 + l2 x2,   comp = exp2(arg2)
// with ln(a_k) and log2(e) folded into the coefficients. Same par4 layout.
// ---------------------------------------------------------------------------
__global__ __launch_bounds__(HT, 2) void head_fused_kernel(
    const float* __restrict__ rep,
    const short* __restrict__ Wpk,
    const float* __restrict__ bmix,
    const float* __restrict__ bmean,
    const float* __restrict__ bscale,
    float* __restrict__ Lout,
    float* __restrict__ par4)
{
    __shared__ float s_red[NWV][64][RST];   // 26.6 KB
    __shared__ float s_c[GR][CSTR];         // 3.1 KB
    __shared__ float s_L[GR][KK][6];        // 1.9 KB

    const int t  = threadIdx.x;
    const int w  = t >> 6;          // wave 0..7
    const int l  = t & 63;
    const int lm = l & 15;
    const int lk = (l >> 4) * 8;
    const int b0 = blockIdx.x * GR;

    // ---- issue ALL loads upfront: 12 Wpk fragments + 8 rep f32x4 ----
    bf16x8 bh[4][3];
#pragma unroll
    for (int kt = 0; kt < 4; ++kt) {
        const int chunk = w * 4 + kt;
#pragma unroll
        for (int nt = 0; nt < 3; ++nt)
            bh[kt][nt] = *(const bf16x8*)(Wpk + (((size_t)chunk * 3 + nt) * 64 + l) * 8);
    }

    f32x4 a0[4], a1[4];
#pragma unroll
    for (int kt = 0; kt < 4; ++kt) {
        const int kof = (w * 4 + kt) * 32 + lk;
        const float* arow = rep + (size_t)(b0 + lm) * DD + kof;
        a0[kt] = *(const f32x4*)(arow);
        a1[kt] = *(const f32x4*)(arow + 4);
    }

    // ---- convert + MFMA ----
    f32x4 acc[3] = {f32x4{0,0,0,0}, f32x4{0,0,0,0}, f32x4{0,0,0,0}};
#pragma unroll
    for (int kt = 0; kt < 4; ++kt) {
        bf16x8 ah;
#pragma unroll
        for (int u = 0; u < 4; ++u) {
            ah[u]     = f2bf(a0[kt][u]);
            ah[u + 4] = f2bf(a1[kt][u]);
        }
#pragma unroll
        for (int nt = 0; nt < 3; ++nt)
            acc[nt] = __builtin_amdgcn_mfma_f32_16x16x32_bf16(ah, bh[kt][nt], acc[nt], 0, 0, 0);
    }

    // ---- 8-deep cross-wave reduce via LDS ----
#pragma unroll
    for (int nt = 0; nt < 3; ++nt)
#pragma unroll
        for (int r = 0; r < 4; ++r)
            s_red[w][l][nt * 4 + r] = acc[nt][r];
    __syncthreads();

    // cooperative sum into s_c[b_loc][j]; C layout [m89]:
    // col(=j) = lane&15, row(=b_loc) = (lane>>4)*4 + reg
    for (int e = t; e < GR * 47; e += HT) {
        const int b_loc = e & 15;
        const int j     = e >> 4;
        const int lane  = ((b_loc >> 2) << 4) | (j & 15);
        const int reg   = ((j >> 4) << 2) | (b_loc & 3);
        float s = 0.f;
#pragma unroll
        for (int q = 0; q < NWV; ++q) s += s_red[q][lane][reg];
        s_c[b_loc][j] = s;
    }
    __syncthreads();

    // ---- tail: 80 threads = 16 b x 5 k ----
    if (t < GR * KK) {
        const int k     = t >> 4;
        const int b_loc = t & 15;
        const int b     = b0 + b_loc;

        float logits[KK];
#pragma unroll
        for (int kk = 0; kk < KK; ++kk) logits[kk] = s_c[b_loc][kk] + bmix[kk];

        float m0 = 0.f, m1 = 0.f, m2 = 0.f;
        if (k > 0) {
            m0 = s_c[b_loc][5 + (k - 1) * 3 + 0] + bmean[(k - 1) * 3 + 0];
            m1 = s_c[b_loc][5 + (k - 1) * 3 + 1] + bmean[(k - 1) * 3 + 1];
            m2 = s_c[b_loc][5 + (k - 1) * 3 + 2] + bmean[(k - 1) * 3 + 2];
        }

        float sc[6];
#pragma unroll
        for (int c = 0; c < 6; ++c)
            sc[c] = s_c[b_loc][17 + k * 6 + c] + bscale[k * 6 + c];

        float mx = logits[0];
#pragma unroll
        for (int kk = 1; kk < KK; ++kk) mx = fmaxf(mx, logits[kk]);
        float den = 0.f;
#pragma unroll
        for (int kk = 0; kk < KK; ++kk) den += expf(logits[kk] - mx);

        const float L00 = softplus_f(sc[0]);
        const float L10 = sc[1];
        const float L11 = softplus_f(sc[2]);
        const float L20 = sc[3];
        const float L21 = sc[4];
        const float L22 = softplus_f(sc[5]);

        const float r00 = 1.f / L00;
        const float r11 = 1.f / L11;
        const float r22 = 1.f / L22;

        s_L[b_loc][k][0] = L00;
        s_L[b_loc][k][1] = L10;
        s_L[b_loc][k][2] = L11;
        s_L[b_loc][k][3] = L20;
        s_L[b_loc][k][4] = L21;
        s_L[b_loc][k][5] = L22;

        // M = L^-1 rows; S = M^T M (symmetric)
        const float m10 = -r11 * L10 * r00;
        const float m20 = r00 * r22 * (L21 * r11 * L10 - L20);
        const float m21 = -r22 * r11 * L21;
        const float s00 = r00 * r00 + m10 * m10 + m20 * m20;
        const float s01 = m10 * r11 + m20 * m21;
        const float s02 = m20 * r22;
        const float s11 = r11 * r11 + m21 * m21;
        const float s12 = m21 * r22;
        const float s22 = r22 * r22;
        const float lin0 = s00 * m0 + s01 * m1 + s02 * m2;
        const float lin1 = s01 * m0 + s11 * m1 + s12 * m2;
        const float lin2 = s02 * m0 + s12 * m1 + s22 * m2;
        const float cm   = m0 * lin0 + m1 * lin1 + m2 * lin2;

        const float lnw = (logits[k] - mx) - logf(den);
        const float c0  = LOG2E * (lnw - logf(L00) - logf(L11) - logf(L22)
                                   - LN2PI15 - 0.5f * cm);

        // poly coefficients (exp2 domain)
        float pv[10] = { -0.5f * LOG2E * s00, -LOG2E * s01, -LOG2E * s02,
                         -0.5f * LOG2E * s11, -LOG2E * s12, -0.5f * LOG2E * s22,
                          LOG2E * lin0,        LOG2E * lin1,  LOG2E * lin2, c0 };
#pragma unroll
        for (int i = 0; i < 10; ++i) {
            const int q = k * 10 + i;
            par4[(((size_t)(q >> 2)) * BB + b) * 4 + (q & 3)] = pv[i];
        }
    }
    __syncthreads();

    // ---- coalesced Lout write: 720 contiguous floats ----
    for (int e = t; e < GR * KK * 9; e += HT) {
        const int b_loc = e / 45;
        const int rem   = e - b_loc * 45;
        const int k     = rem / 9;
        const int e9    = rem - k * 9;
        const int rr    = e9 / 3;
        const int cc    = e9 - rr * 3;
        const float v = (cc > rr) ? 0.f : s_L[b_loc][k][(rr * (rr + 1)) / 2 + cc];
        Lout[(size_t)b0 * 45 + e] = v;
    }
}

// ---------------------------------------------------------------------------
// Kernel 2: eval via per-component quadratic polynomial + native exp2.
// Per point: 6 shared feature muls, then per k: 9 independent FMAs + exp2.
// ---------------------------------------------------------------------------
__global__ __launch_bounds__(256) void eval_kernel(
    const float* __restrict__ dxyz,
    const float* __restrict__ par4,
    float* __restrict__ out)
{
    const int b = blockIdx.x * 256 + threadIdx.x;

    float pr[NG * 4];
#pragma unroll
    for (int g = 0; g < NG; ++g) {
        const f32x4 v = *(const f32x4*)(par4 + ((size_t)g * BB + b) * 4);
        pr[g * 4 + 0] = v[0];
        pr[g * 4 + 1] = v[1];
        pr[g * 4 + 2] = v[2];
        pr[g * 4 + 3] = v[3];
    }

    const int p0 = blockIdx.y * PTS;
    const float* xp = dxyz + ((size_t)p0 * BB + b) * 3;
    float* op = out + (size_t)p0 * BB + b;

#pragma unroll
    for (int i = 0; i < PTS; ++i) {
        const float x0 = xp[0];
        const float x1 = xp[1];
        const float x2 = xp[2];

        const float x00 = x0 * x0, x01 = x0 * x1, x02 = x0 * x2;
        const float x11 = x1 * x1, x12 = x1 * x2, x22 = x2 * x2;

        float res = 0.f;
#pragma unroll
        for (int k = 0; k < KK; ++k) {
            const float* c = pr + k * 10;
            float arg = c[9];
            arg = fmaf(c[0], x00, arg);
            arg = fmaf(c[1], x01, arg);
            arg = fmaf(c[2], x02, arg);
            arg = fmaf(c[3], x11, arg);
            arg = fmaf(c[4], x12, arg);
            arg = fmaf(c[5], x22, arg);
            arg = fmaf(c[6], x0,  arg);
            arg = fmaf(c[7], x1,  arg);
            arg = fmaf(c[8], x2,  arg);
            res += exp2f(arg);
        }
        *op = res;

        xp += (size_t)BB * 3;
        op += BB;
    }
}

extern "C" void kernel_launch(void* const* d_in, const int* in_sizes, int n_in,
                              void* d_out, int out_size, void* d_ws, size_t ws_size,
                              hipStream_t stream) {
    const float* rep    = (const float*)d_in[0];
    const float* dxyz   = (const float*)d_in[1];
    const float* Wmix   = (const float*)d_in[2];
    const float* bmix   = (const float*)d_in[3];
    const float* Wmean  = (const float*)d_in[4];
    const float* bmean  = (const float*)d_in[5];
    const float* Wscale = (const float*)d_in[6];
    const float* bscale = (const float*)d_in[7];

    float* out  = (float*)d_out;
    float* Lout = out + (size_t)BB * PP;          // second tuple output

    float* par4 = (float*)d_ws;                   // NG*BB*4 f32 (852 KB)
    short* Wpk  = (short*)(par4 + (size_t)NG * BB * 4);  // 49152 bf16 (98 KB)

    pack_kernel<<<192, 256, 0, stream>>>(Wmix, Wmean, Wscale, Wpk);

    head_fused_kernel<<<BB / GR, HT, 0, stream>>>(rep, Wpk, bmix, bmean, bscale, Lout, par4);

    eval_kernel<<<dim3(BB / 256, NPT), 256, 0, stream>>>(dxyz, par4, out);
}